// Round 9
// baseline (602.393 us; speedup 1.0000x reference)
//
#include <hip/hip_runtime.h>
#include <cstdint>
#include <cstddef>

// ---------------------------------------------------------------------------
// RezeroGCN round 9: scalar-offset gather — edge offsets broadcast via
// v_readlane (VALU, no LDS pipe) into SGPRs, row gathers issued as
// saddr-form loads (SGPR base + small VGPR offset), uniform SCC loop
// control (no exec masking, no per-16 rounding waste). Odd-edge tail reads
// a zero fp8 row at index N. Everything else identical to round 8.
// ---------------------------------------------------------------------------

constexpr int K = 128;  // IN_C == HID == 128

typedef __bf16 bf16x8 __attribute__((ext_vector_type(8)));
typedef float f32x4 __attribute__((ext_vector_type(4)));
typedef float f32x2 __attribute__((ext_vector_type(2)));

__device__ inline uint16_t f2bf(float f) {
    union { float f; uint32_t u; } c; c.f = f;
    uint32_t r = (c.u + 0x7fffu + ((c.u >> 16) & 1u)) >> 16;
    return (uint16_t)r;
}
__device__ inline float blo(uint32_t u) { union { uint32_t i; float f; } c; c.i = u << 16; return c.f; }
__device__ inline float bhi(uint32_t u) { union { uint32_t i; float f; } c; c.i = u & 0xffff0000u; return c.f; }

// tanh(x) = sign(x)*(1 - 2/(e^{2|x|}+1)); v_exp_f32 + v_rcp_f32.
__device__ inline float fast_tanh(float x) {
    union { float f; uint32_t u; } cx; cx.f = x;
    uint32_t sgn = cx.u & 0x80000000u;
    cx.u &= 0x7fffffffu;
    float t = __expf(2.0f * cx.f);
    float r = fmaf(-2.0f, __builtin_amdgcn_rcpf(t + 1.0f), 1.0f);
    union { float f; uint32_t u; } cr; cr.f = r;
    cr.u |= sgn;
    return cr.f;
}

// ---------------- CSR build: 2-pass counting sort by dst ----------------

__global__ __launch_bounds__(256) void s1_hist(const int* __restrict__ dst,
                                               int* __restrict__ ghist, int E) {
    __shared__ int hist[1024];
    for (int i = threadIdx.x; i < 1024; i += 256) hist[i] = 0;
    __syncthreads();
    int stride = gridDim.x * 256;
    for (int e = blockIdx.x * 256 + threadIdx.x; e < E; e += stride)
        atomicAdd(&hist[dst[e] >> 7], 1);
    __syncthreads();
    for (int i = threadIdx.x; i < 1024; i += 256) {
        int c = hist[i];
        if (c) atomicAdd(&ghist[i], c);
    }
}

__global__ void s2_scan(const int* __restrict__ ghist, int* __restrict__ gbase,
                        int* __restrict__ gcur, int* __restrict__ off, int N, int E) {
    __shared__ int buf[1024];
    int t = threadIdx.x;
    int v = ghist[t];
    buf[t] = v;
    __syncthreads();
    for (int o = 1; o < 1024; o <<= 1) {
        int add = (t >= o) ? buf[t - o] : 0;
        __syncthreads();
        buf[t] += add;
        __syncthreads();
    }
    int ex = buf[t] - v;  // exclusive
    gbase[t] = ex;
    gcur[t] = ex;
    if (t == 1023) gbase[1024] = buf[1023];  // == E
    if (t == 0) off[N] = E;
}

__global__ __launch_bounds__(256) void s3_scatter(
    const int* __restrict__ src, const int* __restrict__ dst,
    int* __restrict__ gcur, int* __restrict__ ebuf, int E)
{
    __shared__ int hist[1024], base[1024], cursor[1024];
    const int t = threadIdx.x;
    const int tile = blockIdx.x * 4096;
    for (int i = t; i < 1024; i += 256) { hist[i] = 0; cursor[i] = 0; }
    __syncthreads();
    int sv[16], dv[16];
#pragma unroll
    for (int k = 0; k < 16; ++k) {
        int e = tile + k * 256 + t;
        bool ok = e < E;
        sv[k] = ok ? src[e] : -1;
        dv[k] = ok ? dst[e] : 0;
        if (ok) atomicAdd(&hist[dv[k] >> 7], 1);
    }
    __syncthreads();
    for (int i = t; i < 1024; i += 256) {
        int c = hist[i];
        base[i] = c ? atomicAdd(&gcur[i], c) : 0;
    }
    __syncthreads();
#pragma unroll
    for (int k = 0; k < 16; ++k) {
        if (sv[k] >= 0) {
            int b = dv[k] >> 7;
            int r = atomicAdd(&cursor[b], 1);
            ebuf[base[b] + r] = (sv[k] << 7) | (dv[k] & 127);
        }
    }
}

// csr entries are BYTE offsets into the fp8 message matrix: src*128 bytes.
__global__ __launch_bounds__(256) void s4_finalize(
    const int* __restrict__ gbase, const int* __restrict__ ebuf,
    int* __restrict__ csr, int* __restrict__ off, float* __restrict__ dinv,
    int N, int E)
{
    __shared__ int hist[128], excl[128], cursor[128];
    const int b = blockIdx.x;
    const int t = threadIdx.x;
    const int lo = gbase[b], hi = gbase[b + 1];
    if (t < 128) hist[t] = 0;
    __syncthreads();
    for (int i = lo + t; i < hi; i += 256) atomicAdd(&hist[ebuf[i] & 127], 1);
    __syncthreads();
    if (t < 128) excl[t] = hist[t];
    __syncthreads();
    for (int o = 1; o < 128; o <<= 1) {
        int v = (t < 128 && t >= o) ? excl[t - o] : 0;
        __syncthreads();
        if (t < 128) excl[t] += v;
        __syncthreads();
    }
    if (t < 128) {
        int node = b * 128 + t;
        int ex = excl[t] - hist[t];
        cursor[t] = ex;
        if (node < N) {
            off[node] = lo + ex;
            dinv[node] = rsqrtf((float)hist[t] + 1.0f);  // +1 self-loop
        }
    }
    __syncthreads();
    for (int i = lo + t; i < hi; i += 256) {
        int v = ebuf[i];
        int r = atomicAdd(&cursor[v & 127], 1);
        csr[lo + r] = v & ~127;  // src<<7 == fp8-row byte offset
    }
}

// ---------------- weight transposes + zero-row init, one launch ----------------

__global__ void wconv_all(const float* __restrict__ Win, const float* __restrict__ Wc,
                          const float* __restrict__ Wo, uint16_t* __restrict__ Tin,
                          uint16_t* __restrict__ Tc, uint16_t* __restrict__ To,
                          uint8_t* __restrict__ Bq8, int N) {
    int idx = blockIdx.x * 256 + threadIdx.x;
    if (idx < 16384) {
        int c = idx >> 7, k = idx & 127;
        Tin[idx] = f2bf(Win[k * 128 + c]);
    } else if (idx < 81920) {
        int t = idx - 16384;
        int l = t >> 14, li = t & 16383;
        int c = li >> 7, k = li & 127;
        Tc[t] = f2bf(Wc[l * 16384 + k * 128 + c]);
    } else if (idx < 90112) {
        int t = idx - 81920;
        int c = t >> 7, k = t & 127;
        To[t] = f2bf(Wo[k * 64 + c]);
    } else if (idx < 90144) {
        // zero fp8 row at index N (gather target for pad edges)
        ((uint32_t*)(Bq8 + (size_t)N * 128))[idx - 90112] = 0u;
    }
}

// ---------------- MFMA GEMM: out[M,NOUT] = A[M,128] @ Wt^T ----------------
// OMODE 0: +bias -> bf16; OMODE 1: +bias -> f32 + fused log_softmax;
// OMODE 2: *rowscale -> fp8 e4m3 messages.
// D frag: lane l, reg i -> row (l>>4)*4 + i, col (l&15)  [verified round 2]

template <int NOUT, bool A_FP32, int OMODE>
__global__ __launch_bounds__(256) void mfma_gemm(
    const void* __restrict__ Aptr, const uint16_t* __restrict__ Wt,
    const float* __restrict__ bias, float* __restrict__ outF,
    uint16_t* __restrict__ outB, uint8_t* __restrict__ outQ,
    const float* __restrict__ rowscale, int M)
{
    constexpr int NT = NOUT / 16;
    const int tid = threadIdx.x;
    const int w = tid >> 6;
    const int l = tid & 63;
    const int lg = l >> 4;   // k-group
    const int lr = l & 15;   // row-in-tile (A) / col-in-tile (B,D)
    const int rbase = blockIdx.x * 128 + w * 32;
    const int r0c = min(rbase + lr, M - 1);
    const int r1c = min(rbase + 16 + lr, M - 1);

    f32x4 acc[2][NT] = {};

    for (int k0 = 0; k0 < K; k0 += 32) {
        const int ka = k0 + lg * 8;
        bf16x8 a0, a1;
        if constexpr (A_FP32) {
            const float* A = (const float*)Aptr;
            const float* p0 = A + (size_t)r0c * K + ka;
            const float* p1 = A + (size_t)r1c * K + ka;
            float4 u0 = *(const float4*)p0, v0 = *(const float4*)(p0 + 4);
            float4 u1 = *(const float4*)p1, v1 = *(const float4*)(p1 + 4);
            a0[0] = (__bf16)u0.x; a0[1] = (__bf16)u0.y; a0[2] = (__bf16)u0.z; a0[3] = (__bf16)u0.w;
            a0[4] = (__bf16)v0.x; a0[5] = (__bf16)v0.y; a0[6] = (__bf16)v0.z; a0[7] = (__bf16)v0.w;
            a1[0] = (__bf16)u1.x; a1[1] = (__bf16)u1.y; a1[2] = (__bf16)u1.z; a1[3] = (__bf16)u1.w;
            a1[4] = (__bf16)v1.x; a1[5] = (__bf16)v1.y; a1[6] = (__bf16)v1.z; a1[7] = (__bf16)v1.w;
        } else {
            const uint16_t* A = (const uint16_t*)Aptr;
            a0 = *reinterpret_cast<const bf16x8*>(A + (size_t)r0c * K + ka);
            a1 = *reinterpret_cast<const bf16x8*>(A + (size_t)r1c * K + ka);
        }
#pragma unroll
        for (int ct = 0; ct < NT; ++ct) {
            bf16x8 b = *reinterpret_cast<const bf16x8*>(Wt + (size_t)(ct * 16 + lr) * K + ka);
            acc[0][ct] = __builtin_amdgcn_mfma_f32_16x16x32_bf16(a0, b, acc[0][ct], 0, 0, 0);
            acc[1][ct] = __builtin_amdgcn_mfma_f32_16x16x32_bf16(a1, b, acc[1][ct], 0, 0, 0);
        }
    }

    float bv[NT];
    if constexpr (OMODE == 0 || OMODE == 1) {
#pragma unroll
        for (int ct = 0; ct < NT; ++ct) bv[ct] = bias[ct * 16 + lr];
    }

    if constexpr (OMODE == 1) {
#pragma unroll
        for (int t = 0; t < 2; ++t) {
#pragma unroll
            for (int i = 0; i < 4; ++i) {
                float v[NT];
                float m = -3.0e38f;
#pragma unroll
                for (int ct = 0; ct < NT; ++ct) {
                    v[ct] = acc[t][ct][i] + bv[ct];
                    m = fmaxf(m, v[ct]);
                }
#pragma unroll
                for (int o = 8; o >= 1; o >>= 1) m = fmaxf(m, __shfl_xor(m, o));
                float s = 0.f;
#pragma unroll
                for (int ct = 0; ct < NT; ++ct) s += __expf(v[ct] - m);
#pragma unroll
                for (int o = 8; o >= 1; o >>= 1) s += __shfl_xor(s, o);
                float lse = m + __logf(s);
                int rr = rbase + t * 16 + lg * 4 + i;
                if (rr < M) {
#pragma unroll
                    for (int ct = 0; ct < NT; ++ct)
                        outF[(size_t)rr * NOUT + ct * 16 + lr] = v[ct] - lse;
                }
            }
        }
    } else {
#pragma unroll
        for (int t = 0; t < 2; ++t) {
#pragma unroll
            for (int i = 0; i < 4; ++i) {
                int rr = rbase + t * 16 + lg * 4 + i;
                if (rr < M) {
                    float sc = 1.0f;
                    if constexpr (OMODE == 2) sc = rowscale[rr];
#pragma unroll
                    for (int ct = 0; ct < NT; ++ct) {
                        float v = acc[t][ct][i];
                        size_t o = (size_t)rr * NOUT + ct * 16 + lr;
                        if constexpr (OMODE == 0) {
                            outB[o] = f2bf(v + bv[ct]);
                        } else {  // OMODE == 2: fp8 e4m3 message
                            v *= sc;
                            int pk = __builtin_amdgcn_cvt_pk_fp8_f32(v, v, 0, false);
                            outQ[o] = (uint8_t)(pk & 0xff);
                        }
                    }
                }
            }
        }
    }
}

// ---------------- aggregation + bias + tanh + rezero (bf16 residual) ----------------
// one wave per node. Per 64-edge chunk: coalesced csr load -> per-pair
// v_readlane into scalars (sA, sB), saddr-form row gathers with VGPR offset
// c0 + (half ? sB-sA : 0). Uniform trip counts (no exec masking); odd tail
// reads the zero row. A[d] = bf16(beta*A[d] + alpha*tanh(dd*(sum+self)+b)).

__global__ __launch_bounds__(256) void agg_kernel(
    const uint8_t* __restrict__ B, uint16_t* __restrict__ A,
    const float* __restrict__ dinv, const int* __restrict__ off,
    const int* __restrict__ csr, const float* __restrict__ bconv,
    const float* __restrict__ alpha, const float* __restrict__ beta,
    int n, int E)
{
    int gid = blockIdx.x * 256 + threadIdx.x;
    int d = gid >> 6;
    int lane = threadIdx.x & 63;
    if (d >= n) return;

    const bool half = (lane >> 5) != 0;
    const int c0 = (lane & 31) * 4;  // 4 features (bytes) per lane
    const int zoff = n << 7;         // byte offset of the zero row
    f32x2 acc01 = {0.f, 0.f}, acc23 = {0.f, 0.f};
    const int s0 = __builtin_amdgcn_readfirstlane(off[d]);
    const int s1 = __builtin_amdgcn_readfirstlane(off[d + 1]);

    for (int j0 = s0; j0 < s1; j0 += 64) {
        int idx = j0 + lane;
        int sv = csr[min(idx, E - 1)];
        sv = (idx < s1) ? sv : zoff;           // pad lanes -> zero row
        const int cnt = min(64, s1 - j0);      // uniform
#pragma unroll 4
        for (int e = 0; e < cnt; e += 2) {
            int sA = __builtin_amdgcn_readlane(sv, e);
            int sB = __builtin_amdgcn_readlane(sv, e + 1);  // ==zoff on odd tail
            int dlt = half ? (sB - sA) : 0;
            uint32_t u = *(const uint32_t*)(B + sA + (c0 + dlt));
            acc01 += __builtin_amdgcn_cvt_pk_f32_fp8((int)u, false);
            acc23 += __builtin_amdgcn_cvt_pk_f32_fp8((int)u, true);
        }
    }
    // self loop (pre-scaled message of d itself)
    {
        uint32_t u = *(const uint32_t*)(B + ((size_t)d << 7) + c0);
        acc01 += __builtin_amdgcn_cvt_pk_f32_fp8((int)u, false);
        acc23 += __builtin_amdgcn_cvt_pk_f32_fp8((int)u, true);
    }
    float a0 = acc01[0], a1 = acc01[1], a2 = acc23[0], a3 = acc23[1];
    // combine the two half-wave partial sums (lane&31 preserved under xor 32)
    a0 += __shfl_xor(a0, 32); a1 += __shfl_xor(a1, 32);
    a2 += __shfl_xor(a2, 32); a3 += __shfl_xor(a3, 32);

    // self-loop counted twice (once per half) -> subtract one copy
    {
        uint32_t u = *(const uint32_t*)(B + ((size_t)d << 7) + c0);
        f32x2 lo = __builtin_amdgcn_cvt_pk_f32_fp8((int)u, false);
        f32x2 hi = __builtin_amdgcn_cvt_pk_f32_fp8((int)u, true);
        a0 -= lo[0]; a1 -= lo[1]; a2 -= hi[0]; a3 -= hi[1];
    }

    float dd = dinv[d];
    float al = alpha[0], be = beta[0];
    float4 bb = *(const float4*)(bconv + c0);
    uint2 ip = *(const uint2*)(A + (size_t)d * K + c0);
    float o0 = be * blo(ip.x) + al * fast_tanh(fmaf(dd, a0, bb.x));
    float o1 = be * bhi(ip.x) + al * fast_tanh(fmaf(dd, a1, bb.y));
    float o2 = be * blo(ip.y) + al * fast_tanh(fmaf(dd, a2, bb.z));
    float o3 = be * bhi(ip.y) + al * fast_tanh(fmaf(dd, a3, bb.w));
    if (!half) {
        uint2 pk;
        asm("v_cvt_pk_bf16_f32 %0, %1, %2" : "=v"(pk.x) : "v"(o0), "v"(o1));
        asm("v_cvt_pk_bf16_f32 %0, %1, %2" : "=v"(pk.y) : "v"(o2), "v"(o3));
        *(uint2*)(A + (size_t)d * K + c0) = pk;
    }
}

// ---------------------------------------------------------------------------

extern "C" void kernel_launch(void* const* d_in, const int* in_sizes, int n_in,
                              void* d_out, int out_size, void* d_ws, size_t ws_size,
                              hipStream_t stream)
{
    const float* x      = (const float*)d_in[0];
    const int*   ei     = (const int*)d_in[1];
    const float* W_in   = (const float*)d_in[2];
    const float* b_in   = (const float*)d_in[3];
    const float* W_conv = (const float*)d_in[4];
    const float* b_conv = (const float*)d_in[5];
    const float* alpha  = (const float*)d_in[6];
    const float* beta   = (const float*)d_in[7];
    const float* W_out  = (const float*)d_in[8];
    const float* b_out  = (const float*)d_in[9];
    float* out = (float*)d_out;

    const int N = in_sizes[0] / K;   // 100000
    const int E = in_sizes[1] / 2;   // 1600000
    const int L = in_sizes[6];       // 4

    const int* src = ei;
    const int* dst = ei + E;

    // workspace carve (16B-aligned by construction)
    char* p = (char*)d_ws;
    uint16_t* Abf = (uint16_t*)p;      p += (size_t)N * K * sizeof(uint16_t);     // 25.6 MB
    uint8_t* Bq8 = (uint8_t*)p;        p += (size_t)(N + 1) * K * sizeof(uint8_t);// 12.8 MB + zero row
    p = (char*)(((uintptr_t)p + 15) & ~(uintptr_t)15);
    uint16_t* Wt_in = (uint16_t*)p;    p += (size_t)K * K * sizeof(uint16_t);
    uint16_t* Wt_conv = (uint16_t*)p;  p += (size_t)4 * K * K * sizeof(uint16_t);
    uint16_t* Wt_out = (uint16_t*)p;   p += (size_t)64 * K * sizeof(uint16_t);
    float* dinv = (float*)p;           p += (size_t)N * sizeof(float);
    int* off = (int*)p;                p += (size_t)(N + 1) * sizeof(int);
    int* csr = (int*)p;                p += (size_t)E * sizeof(int);
    int* ghist = (int*)p;              p += 1024 * sizeof(int);
    int* gbase = (int*)p;              p += 1025 * sizeof(int);
    int* gcur = (int*)p;               p += 1024 * sizeof(int);
    int* ebuf = (int*)p;               p += (size_t)E * sizeof(int);  // CSR-build staging

    // ---- CSR build (counting sort by dst) ----
    hipMemsetAsync(ghist, 0, 1024 * sizeof(int), stream);
    s1_hist<<<256, 256, 0, stream>>>(dst, ghist, E);
    s2_scan<<<1, 1024, 0, stream>>>(ghist, gbase, gcur, off, N, E);
    s3_scatter<<<(E + 4095) / 4096, 256, 0, stream>>>(src, dst, gcur, ebuf, E);
    s4_finalize<<<(N + 127) / 128, 256, 0, stream>>>(gbase, ebuf, csr, off, dinv, N, E);

    wconv_all<<<(90144 + 255) / 256, 256, 0, stream>>>(
        W_in, W_conv, W_out, Wt_in, Wt_conv, Wt_out, Bq8, N);

    const int gblocks = (N + 127) / 128;
    // h0 = x @ W_in + b_in  -> Abf (bf16 residual)
    mfma_gemm<128, true, 0><<<gblocks, 256, 0, stream>>>(
        x, Wt_in, b_in, nullptr, Abf, nullptr, nullptr, N);
    for (int l = 0; l < L; ++l) {
        // Bq8 = fp8( dinv[row] * (Abf @ Wc) )   (pre-scaled messages)
        mfma_gemm<128, false, 2><<<gblocks, 256, 0, stream>>>(
            Abf, Wt_conv + (size_t)l * K * K, nullptr, nullptr, nullptr, Bq8, dinv, N);
        agg_kernel<<<(N * 64 + 255) / 256, 256, 0, stream>>>(
            Bq8, Abf, dinv, off, csr, b_conv + (size_t)l * K,
            alpha + l, beta + l, N, E);
    }
    // logits = Abf @ W_out + b_out, fused log_softmax, fp32 to d_out
    mfma_gemm<64, false, 1><<<gblocks, 256, 0, stream>>>(
        Abf, Wt_out, b_out, out, nullptr, nullptr, nullptr, N);
}

// Round 10
// 494.383 us; speedup vs baseline: 1.2185x; 1.2185x over previous
//
#include <hip/hip_runtime.h>
#include <cstdint>
#include <cstddef>

// ---------------------------------------------------------------------------
// RezeroGCN round 10: revert to round-8 gather (bpermute broadcast keeps the
// LDS pipe busy, VALU free; 4 loads in flight) + cut pad waste: full 8-edge
// batches unpredicated, single predicated tail batch. Self-loop added once
// AFTER the half-wave combine (round-8 double-count fixed). fp8 messages,
// byte-offset CSR, counting-sort build, MFMA GEMMs unchanged.
// ---------------------------------------------------------------------------

constexpr int K = 128;  // IN_C == HID == 128

typedef __bf16 bf16x8 __attribute__((ext_vector_type(8)));
typedef float f32x4 __attribute__((ext_vector_type(4)));
typedef float f32x2 __attribute__((ext_vector_type(2)));

__device__ inline uint16_t f2bf(float f) {
    union { float f; uint32_t u; } c; c.f = f;
    uint32_t r = (c.u + 0x7fffu + ((c.u >> 16) & 1u)) >> 16;
    return (uint16_t)r;
}
__device__ inline float blo(uint32_t u) { union { uint32_t i; float f; } c; c.i = u << 16; return c.f; }
__device__ inline float bhi(uint32_t u) { union { uint32_t i; float f; } c; c.i = u & 0xffff0000u; return c.f; }

// tanh(x) = sign(x)*(1 - 2/(e^{2|x|}+1)); v_exp_f32 + v_rcp_f32.
__device__ inline float fast_tanh(float x) {
    union { float f; uint32_t u; } cx; cx.f = x;
    uint32_t sgn = cx.u & 0x80000000u;
    cx.u &= 0x7fffffffu;
    float t = __expf(2.0f * cx.f);
    float r = fmaf(-2.0f, __builtin_amdgcn_rcpf(t + 1.0f), 1.0f);
    union { float f; uint32_t u; } cr; cr.f = r;
    cr.u |= sgn;
    return cr.f;
}

// ---------------- CSR build: 2-pass counting sort by dst ----------------

__global__ __launch_bounds__(256) void s1_hist(const int* __restrict__ dst,
                                               int* __restrict__ ghist, int E) {
    __shared__ int hist[1024];
    for (int i = threadIdx.x; i < 1024; i += 256) hist[i] = 0;
    __syncthreads();
    int stride = gridDim.x * 256;
    for (int e = blockIdx.x * 256 + threadIdx.x; e < E; e += stride)
        atomicAdd(&hist[dst[e] >> 7], 1);
    __syncthreads();
    for (int i = threadIdx.x; i < 1024; i += 256) {
        int c = hist[i];
        if (c) atomicAdd(&ghist[i], c);
    }
}

__global__ void s2_scan(const int* __restrict__ ghist, int* __restrict__ gbase,
                        int* __restrict__ gcur, int* __restrict__ off, int N, int E) {
    __shared__ int buf[1024];
    int t = threadIdx.x;
    int v = ghist[t];
    buf[t] = v;
    __syncthreads();
    for (int o = 1; o < 1024; o <<= 1) {
        int add = (t >= o) ? buf[t - o] : 0;
        __syncthreads();
        buf[t] += add;
        __syncthreads();
    }
    int ex = buf[t] - v;  // exclusive
    gbase[t] = ex;
    gcur[t] = ex;
    if (t == 1023) gbase[1024] = buf[1023];  // == E
    if (t == 0) off[N] = E;
}

__global__ __launch_bounds__(256) void s3_scatter(
    const int* __restrict__ src, const int* __restrict__ dst,
    int* __restrict__ gcur, int* __restrict__ ebuf, int E)
{
    __shared__ int hist[1024], base[1024], cursor[1024];
    const int t = threadIdx.x;
    const int tile = blockIdx.x * 4096;
    for (int i = t; i < 1024; i += 256) { hist[i] = 0; cursor[i] = 0; }
    __syncthreads();
    int sv[16], dv[16];
#pragma unroll
    for (int k = 0; k < 16; ++k) {
        int e = tile + k * 256 + t;
        bool ok = e < E;
        sv[k] = ok ? src[e] : -1;
        dv[k] = ok ? dst[e] : 0;
        if (ok) atomicAdd(&hist[dv[k] >> 7], 1);
    }
    __syncthreads();
    for (int i = t; i < 1024; i += 256) {
        int c = hist[i];
        base[i] = c ? atomicAdd(&gcur[i], c) : 0;
    }
    __syncthreads();
#pragma unroll
    for (int k = 0; k < 16; ++k) {
        if (sv[k] >= 0) {
            int b = dv[k] >> 7;
            int r = atomicAdd(&cursor[b], 1);
            ebuf[base[b] + r] = (sv[k] << 7) | (dv[k] & 127);
        }
    }
}

// csr entries are BYTE offsets into the fp8 message matrix: src*128 bytes.
__global__ __launch_bounds__(256) void s4_finalize(
    const int* __restrict__ gbase, const int* __restrict__ ebuf,
    int* __restrict__ csr, int* __restrict__ off, float* __restrict__ dinv,
    int N, int E)
{
    __shared__ int hist[128], excl[128], cursor[128];
    const int b = blockIdx.x;
    const int t = threadIdx.x;
    const int lo = gbase[b], hi = gbase[b + 1];
    if (t < 128) hist[t] = 0;
    __syncthreads();
    for (int i = lo + t; i < hi; i += 256) atomicAdd(&hist[ebuf[i] & 127], 1);
    __syncthreads();
    if (t < 128) excl[t] = hist[t];
    __syncthreads();
    for (int o = 1; o < 128; o <<= 1) {
        int v = (t < 128 && t >= o) ? excl[t - o] : 0;
        __syncthreads();
        if (t < 128) excl[t] += v;
        __syncthreads();
    }
    if (t < 128) {
        int node = b * 128 + t;
        int ex = excl[t] - hist[t];
        cursor[t] = ex;
        if (node < N) {
            off[node] = lo + ex;
            dinv[node] = rsqrtf((float)hist[t] + 1.0f);  // +1 self-loop
        }
    }
    __syncthreads();
    for (int i = lo + t; i < hi; i += 256) {
        int v = ebuf[i];
        int r = atomicAdd(&cursor[v & 127], 1);
        csr[lo + r] = v & ~127;  // src<<7 == fp8-row byte offset
    }
}

// ---------------- all weight transposes in one launch ----------------

__global__ void wconv_all(const float* __restrict__ Win, const float* __restrict__ Wc,
                          const float* __restrict__ Wo, uint16_t* __restrict__ Tin,
                          uint16_t* __restrict__ Tc, uint16_t* __restrict__ To) {
    int idx = blockIdx.x * 256 + threadIdx.x;
    if (idx < 16384) {
        int c = idx >> 7, k = idx & 127;
        Tin[idx] = f2bf(Win[k * 128 + c]);
    } else if (idx < 81920) {
        int t = idx - 16384;
        int l = t >> 14, li = t & 16383;
        int c = li >> 7, k = li & 127;
        Tc[t] = f2bf(Wc[l * 16384 + k * 128 + c]);
    } else if (idx < 90112) {
        int t = idx - 81920;
        int c = t >> 7, k = t & 127;
        To[t] = f2bf(Wo[k * 64 + c]);
    }
}

// ---------------- MFMA GEMM: out[M,NOUT] = A[M,128] @ Wt^T ----------------
// OMODE 0: +bias -> bf16; OMODE 1: +bias -> f32 + fused log_softmax;
// OMODE 2: *rowscale -> fp8 e4m3 messages.
// D frag: lane l, reg i -> row (l>>4)*4 + i, col (l&15)  [verified round 2]

template <int NOUT, bool A_FP32, int OMODE>
__global__ __launch_bounds__(256) void mfma_gemm(
    const void* __restrict__ Aptr, const uint16_t* __restrict__ Wt,
    const float* __restrict__ bias, float* __restrict__ outF,
    uint16_t* __restrict__ outB, uint8_t* __restrict__ outQ,
    const float* __restrict__ rowscale, int M)
{
    constexpr int NT = NOUT / 16;
    const int tid = threadIdx.x;
    const int w = tid >> 6;
    const int l = tid & 63;
    const int lg = l >> 4;   // k-group
    const int lr = l & 15;   // row-in-tile (A) / col-in-tile (B,D)
    const int rbase = blockIdx.x * 128 + w * 32;
    const int r0c = min(rbase + lr, M - 1);
    const int r1c = min(rbase + 16 + lr, M - 1);

    f32x4 acc[2][NT] = {};

    for (int k0 = 0; k0 < K; k0 += 32) {
        const int ka = k0 + lg * 8;
        bf16x8 a0, a1;
        if constexpr (A_FP32) {
            const float* A = (const float*)Aptr;
            const float* p0 = A + (size_t)r0c * K + ka;
            const float* p1 = A + (size_t)r1c * K + ka;
            float4 u0 = *(const float4*)p0, v0 = *(const float4*)(p0 + 4);
            float4 u1 = *(const float4*)p1, v1 = *(const float4*)(p1 + 4);
            a0[0] = (__bf16)u0.x; a0[1] = (__bf16)u0.y; a0[2] = (__bf16)u0.z; a0[3] = (__bf16)u0.w;
            a0[4] = (__bf16)v0.x; a0[5] = (__bf16)v0.y; a0[6] = (__bf16)v0.z; a0[7] = (__bf16)v0.w;
            a1[0] = (__bf16)u1.x; a1[1] = (__bf16)u1.y; a1[2] = (__bf16)u1.z; a1[3] = (__bf16)u1.w;
            a1[4] = (__bf16)v1.x; a1[5] = (__bf16)v1.y; a1[6] = (__bf16)v1.z; a1[7] = (__bf16)v1.w;
        } else {
            const uint16_t* A = (const uint16_t*)Aptr;
            a0 = *reinterpret_cast<const bf16x8*>(A + (size_t)r0c * K + ka);
            a1 = *reinterpret_cast<const bf16x8*>(A + (size_t)r1c * K + ka);
        }
#pragma unroll
        for (int ct = 0; ct < NT; ++ct) {
            bf16x8 b = *reinterpret_cast<const bf16x8*>(Wt + (size_t)(ct * 16 + lr) * K + ka);
            acc[0][ct] = __builtin_amdgcn_mfma_f32_16x16x32_bf16(a0, b, acc[0][ct], 0, 0, 0);
            acc[1][ct] = __builtin_amdgcn_mfma_f32_16x16x32_bf16(a1, b, acc[1][ct], 0, 0, 0);
        }
    }

    float bv[NT];
    if constexpr (OMODE == 0 || OMODE == 1) {
#pragma unroll
        for (int ct = 0; ct < NT; ++ct) bv[ct] = bias[ct * 16 + lr];
    }

    if constexpr (OMODE == 1) {
#pragma unroll
        for (int t = 0; t < 2; ++t) {
#pragma unroll
            for (int i = 0; i < 4; ++i) {
                float v[NT];
                float m = -3.0e38f;
#pragma unroll
                for (int ct = 0; ct < NT; ++ct) {
                    v[ct] = acc[t][ct][i] + bv[ct];
                    m = fmaxf(m, v[ct]);
                }
#pragma unroll
                for (int o = 8; o >= 1; o >>= 1) m = fmaxf(m, __shfl_xor(m, o));
                float s = 0.f;
#pragma unroll
                for (int ct = 0; ct < NT; ++ct) s += __expf(v[ct] - m);
#pragma unroll
                for (int o = 8; o >= 1; o >>= 1) s += __shfl_xor(s, o);
                float lse = m + __logf(s);
                int rr = rbase + t * 16 + lg * 4 + i;
                if (rr < M) {
#pragma unroll
                    for (int ct = 0; ct < NT; ++ct)
                        outF[(size_t)rr * NOUT + ct * 16 + lr] = v[ct] - lse;
                }
            }
        }
    } else {
#pragma unroll
        for (int t = 0; t < 2; ++t) {
#pragma unroll
            for (int i = 0; i < 4; ++i) {
                int rr = rbase + t * 16 + lg * 4 + i;
                if (rr < M) {
                    float sc = 1.0f;
                    if constexpr (OMODE == 2) sc = rowscale[rr];
#pragma unroll
                    for (int ct = 0; ct < NT; ++ct) {
                        float v = acc[t][ct][i];
                        size_t o = (size_t)rr * NOUT + ct * 16 + lr;
                        if constexpr (OMODE == 0) {
                            outB[o] = f2bf(v + bv[ct]);
                        } else {  // OMODE == 2: fp8 e4m3 message
                            v *= sc;
                            int pk = __builtin_amdgcn_cvt_pk_fp8_f32(v, v, 0, false);
                            outQ[o] = (uint8_t)(pk & 0xff);
                        }
                    }
                }
            }
        }
    }
}

// ---------------- aggregation + bias + tanh + rezero (bf16 residual) ----------------
// one wave per node. fp8 pre-scaled messages (128B/row), byte-offset csr.
// Half-wave 0 = even edges, half-wave 1 = odd edges; 4B/lane = 4 features.
// Full 8-edge batches (4 loads, unpredicated) + one predicated tail batch;
// self-loop added ONCE after the half-wave combine.

__global__ __launch_bounds__(256) void agg_kernel(
    const uint8_t* __restrict__ B, uint16_t* __restrict__ A,
    const float* __restrict__ dinv, const int* __restrict__ off,
    const int* __restrict__ csr, const float* __restrict__ bconv,
    const float* __restrict__ alpha, const float* __restrict__ beta,
    int n, int E)
{
    int gid = blockIdx.x * 256 + threadIdx.x;
    int d = gid >> 6;
    int lane = threadIdx.x & 63;
    if (d >= n) return;

    const int half = lane >> 5;
    const int c0 = (lane & 31) * 4;  // 4 features (bytes) per lane
    f32x2 acc01 = {0.f, 0.f}, acc23 = {0.f, 0.f};
    const int s0 = off[d], s1 = off[d + 1];

    for (int j0 = s0; j0 < s1; j0 += 64) {
        int idx = j0 + lane;
        int sv = csr[min(idx, E - 1)];  // byte offset of src row
        const int cnt = min(64, s1 - j0);
        const int cf = cnt & ~7;
        int it = 0;
        for (; it < cf; it += 8) {      // full batch: 8 edges, 4 loads, no masks
            uint32_t u[4];
#pragma unroll
            for (int q = 0; q < 4; ++q) {
                int o = __shfl(sv, it + 2 * q + half);
                u[q] = *(const uint32_t*)(B + o + c0);
            }
#pragma unroll
            for (int q = 0; q < 4; ++q) {
                acc01 += __builtin_amdgcn_cvt_pk_f32_fp8((int)u[q], false);
                acc23 += __builtin_amdgcn_cvt_pk_f32_fp8((int)u[q], true);
            }
        }
        if (it < cnt) {                 // tail batch: predicated
            uint32_t u[4];
#pragma unroll
            for (int q = 0; q < 4; ++q) {
                int e = it + 2 * q + half;
                int o = __shfl(sv, e);
                u[q] = (e < cnt) ? *(const uint32_t*)(B + o + c0) : 0u;
            }
#pragma unroll
            for (int q = 0; q < 4; ++q) {
                acc01 += __builtin_amdgcn_cvt_pk_f32_fp8((int)u[q], false);
                acc23 += __builtin_amdgcn_cvt_pk_f32_fp8((int)u[q], true);
            }
        }
    }
    float a0 = acc01[0], a1 = acc01[1], a2 = acc23[0], a3 = acc23[1];
    // combine the two half-wave partial sums (lane&31 preserved under xor 32)
    a0 += __shfl_xor(a0, 32); a1 += __shfl_xor(a1, 32);
    a2 += __shfl_xor(a2, 32); a3 += __shfl_xor(a3, 32);
    // self loop, added once AFTER the combine
    {
        uint32_t u = *(const uint32_t*)(B + ((size_t)d << 7) + c0);
        f32x2 lo = __builtin_amdgcn_cvt_pk_f32_fp8((int)u, false);
        f32x2 hi = __builtin_amdgcn_cvt_pk_f32_fp8((int)u, true);
        a0 += lo[0]; a1 += lo[1]; a2 += hi[0]; a3 += hi[1];
    }

    float dd = dinv[d];
    float al = alpha[0], be = beta[0];
    float4 bb = *(const float4*)(bconv + c0);
    uint2 ip = *(const uint2*)(A + (size_t)d * K + c0);
    float o0 = be * blo(ip.x) + al * fast_tanh(fmaf(dd, a0, bb.x));
    float o1 = be * bhi(ip.x) + al * fast_tanh(fmaf(dd, a1, bb.y));
    float o2 = be * blo(ip.y) + al * fast_tanh(fmaf(dd, a2, bb.z));
    float o3 = be * bhi(ip.y) + al * fast_tanh(fmaf(dd, a3, bb.w));
    if (half == 0) {
        uint2 pk;
        asm("v_cvt_pk_bf16_f32 %0, %1, %2" : "=v"(pk.x) : "v"(o0), "v"(o1));
        asm("v_cvt_pk_bf16_f32 %0, %1, %2" : "=v"(pk.y) : "v"(o2), "v"(o3));
        *(uint2*)(A + (size_t)d * K + c0) = pk;
    }
}

// ---------------------------------------------------------------------------

extern "C" void kernel_launch(void* const* d_in, const int* in_sizes, int n_in,
                              void* d_out, int out_size, void* d_ws, size_t ws_size,
                              hipStream_t stream)
{
    const float* x      = (const float*)d_in[0];
    const int*   ei     = (const int*)d_in[1];
    const float* W_in   = (const float*)d_in[2];
    const float* b_in   = (const float*)d_in[3];
    const float* W_conv = (const float*)d_in[4];
    const float* b_conv = (const float*)d_in[5];
    const float* alpha  = (const float*)d_in[6];
    const float* beta   = (const float*)d_in[7];
    const float* W_out  = (const float*)d_in[8];
    const float* b_out  = (const float*)d_in[9];
    float* out = (float*)d_out;

    const int N = in_sizes[0] / K;   // 100000
    const int E = in_sizes[1] / 2;   // 1600000
    const int L = in_sizes[6];       // 4

    const int* src = ei;
    const int* dst = ei + E;

    // workspace carve (16B-aligned by construction)
    char* p = (char*)d_ws;
    uint16_t* Abf = (uint16_t*)p;      p += (size_t)N * K * sizeof(uint16_t);  // 25.6 MB
    uint8_t* Bq8 = (uint8_t*)p;        p += (size_t)N * K * sizeof(uint8_t);   // 12.8 MB
    uint16_t* Wt_in = (uint16_t*)p;    p += (size_t)K * K * sizeof(uint16_t);
    uint16_t* Wt_conv = (uint16_t*)p;  p += (size_t)4 * K * K * sizeof(uint16_t);
    uint16_t* Wt_out = (uint16_t*)p;   p += (size_t)64 * K * sizeof(uint16_t);
    float* dinv = (float*)p;           p += (size_t)N * sizeof(float);
    int* off = (int*)p;                p += (size_t)(N + 1) * sizeof(int);
    int* csr = (int*)p;                p += (size_t)E * sizeof(int);
    int* ghist = (int*)p;              p += 1024 * sizeof(int);
    int* gbase = (int*)p;              p += 1025 * sizeof(int);
    int* gcur = (int*)p;               p += 1024 * sizeof(int);
    int* ebuf = (int*)p;               p += (size_t)E * sizeof(int);  // CSR-build staging

    // ---- CSR build (counting sort by dst) ----
    hipMemsetAsync(ghist, 0, 1024 * sizeof(int), stream);
    s1_hist<<<256, 256, 0, stream>>>(dst, ghist, E);
    s2_scan<<<1, 1024, 0, stream>>>(ghist, gbase, gcur, off, N, E);
    s3_scatter<<<(E + 4095) / 4096, 256, 0, stream>>>(src, dst, gcur, ebuf, E);
    s4_finalize<<<(N + 127) / 128, 256, 0, stream>>>(gbase, ebuf, csr, off, dinv, N, E);

    wconv_all<<<(90112 + 255) / 256, 256, 0, stream>>>(
        W_in, W_conv, W_out, Wt_in, Wt_conv, Wt_out);

    const int gblocks = (N + 127) / 128;
    // h0 = x @ W_in + b_in  -> Abf (bf16 residual)
    mfma_gemm<128, true, 0><<<gblocks, 256, 0, stream>>>(
        x, Wt_in, b_in, nullptr, Abf, nullptr, nullptr, N);
    for (int l = 0; l < L; ++l) {
        // Bq8 = fp8( dinv[row] * (Abf @ Wc) )   (pre-scaled messages)
        mfma_gemm<128, false, 2><<<gblocks, 256, 0, stream>>>(
            Abf, Wt_conv + (size_t)l * K * K, nullptr, nullptr, nullptr, Bq8, dinv, N);
        agg_kernel<<<(N * 64 + 255) / 256, 256, 0, stream>>>(
            Bq8, Abf, dinv, off, csr, b_conv + (size_t)l * K,
            alpha + l, beta + l, N, E);
    }
    // logits = Abf @ W_out + b_out, fused log_softmax, fp32 to d_out
    mfma_gemm<64, false, 1><<<gblocks, 256, 0, stream>>>(
        Abf, Wt_out, b_out, out, nullptr, nullptr, nullptr, N);
}

// Round 11
// 488.892 us; speedup vs baseline: 1.2322x; 1.0112x over previous
//
#include <hip/hip_runtime.h>
#include <cstdint>
#include <cstddef>

// ---------------------------------------------------------------------------
// RezeroGCN round 11: agg is at its structural floor (L3 random 128B-line
// rate; 2 reads/row/XCD caps L2 hit at the observed 50%). This round attacks
// the other ~309us: fuse independent stages (s1+wconv; input-GEMM+s3),
// s3 tile 4096->8192 (coarser write runs), 16 -> 13 launches.
// agg / GEMM math unchanged from round 10.
// ---------------------------------------------------------------------------

constexpr int K = 128;  // IN_C == HID == 128

typedef __bf16 bf16x8 __attribute__((ext_vector_type(8)));
typedef float f32x4 __attribute__((ext_vector_type(4)));
typedef float f32x2 __attribute__((ext_vector_type(2)));

__device__ inline uint16_t f2bf(float f) {
    union { float f; uint32_t u; } c; c.f = f;
    uint32_t r = (c.u + 0x7fffu + ((c.u >> 16) & 1u)) >> 16;
    return (uint16_t)r;
}
__device__ inline float blo(uint32_t u) { union { uint32_t i; float f; } c; c.i = u << 16; return c.f; }
__device__ inline float bhi(uint32_t u) { union { uint32_t i; float f; } c; c.i = u & 0xffff0000u; return c.f; }

// tanh(x) = sign(x)*(1 - 2/(e^{2|x|}+1)); v_exp_f32 + v_rcp_f32.
__device__ inline float fast_tanh(float x) {
    union { float f; uint32_t u; } cx; cx.f = x;
    uint32_t sgn = cx.u & 0x80000000u;
    cx.u &= 0x7fffffffu;
    float t = __expf(2.0f * cx.f);
    float r = fmaf(-2.0f, __builtin_amdgcn_rcpf(t + 1.0f), 1.0f);
    union { float f; uint32_t u; } cr; cr.f = r;
    cr.u |= sgn;
    return cr.f;
}

// ---------------- CSR build bodies ----------------

__device__ __forceinline__ void s1_body(int bid, const int* __restrict__ dst,
                                        int* __restrict__ ghist, int E) {
    __shared__ int hist[1024];
    for (int i = threadIdx.x; i < 1024; i += 256) hist[i] = 0;
    __syncthreads();
    int stride = 256 * 256;
    for (int e = bid * 256 + threadIdx.x; e < E; e += stride)
        atomicAdd(&hist[dst[e] >> 7], 1);
    __syncthreads();
    for (int i = threadIdx.x; i < 1024; i += 256) {
        int c = hist[i];
        if (c) atomicAdd(&ghist[i], c);
    }
}

__device__ __forceinline__ void wconv_body(int bid, const float* __restrict__ Win,
                                           const float* __restrict__ Wc,
                                           const float* __restrict__ Wo,
                                           uint16_t* __restrict__ Tin,
                                           uint16_t* __restrict__ Tc,
                                           uint16_t* __restrict__ To) {
    int idx = bid * 256 + threadIdx.x;
    if (idx < 16384) {
        int c = idx >> 7, k = idx & 127;
        Tin[idx] = f2bf(Win[k * 128 + c]);
    } else if (idx < 81920) {
        int t = idx - 16384;
        int l = t >> 14, li = t & 16383;
        int c = li >> 7, k = li & 127;
        Tc[t] = f2bf(Wc[l * 16384 + k * 128 + c]);
    } else if (idx < 90112) {
        int t = idx - 81920;
        int c = t >> 7, k = t & 127;
        To[t] = f2bf(Wo[k * 64 + c]);
    }
}

// k1: s1 histogram (blocks 0..255) + weight transposes (blocks 256..607)
__global__ __launch_bounds__(256) void fused_s1_wconv(
    const int* __restrict__ dst, int* __restrict__ ghist, int E,
    const float* __restrict__ Win, const float* __restrict__ Wc,
    const float* __restrict__ Wo, uint16_t* __restrict__ Tin,
    uint16_t* __restrict__ Tc, uint16_t* __restrict__ To)
{
    int b = blockIdx.x;
    if (b < 256) s1_body(b, dst, ghist, E);
    else wconv_body(b - 256, Win, Wc, Wo, Tin, Tc, To);
}

__global__ void s2_scan(const int* __restrict__ ghist, int* __restrict__ gbase,
                        int* __restrict__ gcur, int* __restrict__ off, int N, int E) {
    __shared__ int buf[1024];
    int t = threadIdx.x;
    int v = ghist[t];
    buf[t] = v;
    __syncthreads();
    for (int o = 1; o < 1024; o <<= 1) {
        int add = (t >= o) ? buf[t - o] : 0;
        __syncthreads();
        buf[t] += add;
        __syncthreads();
    }
    int ex = buf[t] - v;  // exclusive
    gbase[t] = ex;
    gcur[t] = ex;
    if (t == 1023) gbase[1024] = buf[1023];  // == E
    if (t == 0) off[N] = E;
}

// s3: 8192-edge tiles, 32 edges/thread; LDS hist + one global reservation
// per (block,bucket); packed (src<<7)|(dst&127) into ebuf.
__device__ __forceinline__ void s3_body(int bid, const int* __restrict__ src,
                                        const int* __restrict__ dst,
                                        int* __restrict__ gcur,
                                        int* __restrict__ ebuf, int E) {
    __shared__ int hist[1024], base[1024], cursor[1024];
    const int t = threadIdx.x;
    const int tile = bid * 8192;
    for (int i = t; i < 1024; i += 256) { hist[i] = 0; cursor[i] = 0; }
    __syncthreads();
    int sv[32], dv[32];
#pragma unroll
    for (int k = 0; k < 32; ++k) {
        int e = tile + k * 256 + t;
        bool ok = e < E;
        sv[k] = ok ? src[e] : -1;
        dv[k] = ok ? dst[e] : 0;
        if (ok) atomicAdd(&hist[dv[k] >> 7], 1);
    }
    __syncthreads();
    for (int i = t; i < 1024; i += 256) {
        int c = hist[i];
        base[i] = c ? atomicAdd(&gcur[i], c) : 0;
    }
    __syncthreads();
#pragma unroll
    for (int k = 0; k < 32; ++k) {
        if (sv[k] >= 0) {
            int b = dv[k] >> 7;
            int r = atomicAdd(&cursor[b], 1);
            ebuf[base[b] + r] = (sv[k] << 7) | (dv[k] & 127);
        }
    }
}

// csr entries are BYTE offsets into the fp8 message matrix: src*128 bytes.
__global__ __launch_bounds__(256) void s4_finalize(
    const int* __restrict__ gbase, const int* __restrict__ ebuf,
    int* __restrict__ csr, int* __restrict__ off, float* __restrict__ dinv,
    int N, int E)
{
    __shared__ int hist[128], excl[128], cursor[128];
    const int b = blockIdx.x;
    const int t = threadIdx.x;
    const int lo = gbase[b], hi = gbase[b + 1];
    if (t < 128) hist[t] = 0;
    __syncthreads();
    for (int i = lo + t; i < hi; i += 256) atomicAdd(&hist[ebuf[i] & 127], 1);
    __syncthreads();
    if (t < 128) excl[t] = hist[t];
    __syncthreads();
    for (int o = 1; o < 128; o <<= 1) {
        int v = (t < 128 && t >= o) ? excl[t - o] : 0;
        __syncthreads();
        if (t < 128) excl[t] += v;
        __syncthreads();
    }
    if (t < 128) {
        int node = b * 128 + t;
        int ex = excl[t] - hist[t];
        cursor[t] = ex;
        if (node < N) {
            off[node] = lo + ex;
            dinv[node] = rsqrtf((float)hist[t] + 1.0f);  // +1 self-loop
        }
    }
    __syncthreads();
    for (int i = lo + t; i < hi; i += 256) {
        int v = ebuf[i];
        int r = atomicAdd(&cursor[v & 127], 1);
        csr[lo + r] = v & ~127;  // src<<7 == fp8-row byte offset
    }
}

// ---------------- MFMA GEMM body: out[bid-tile] = A @ Wt^T ----------------
// OMODE 0: +bias -> bf16; OMODE 1: +bias -> f32 + fused log_softmax;
// OMODE 2: *rowscale -> fp8 e4m3 messages.
// D frag: lane l, reg i -> row (l>>4)*4 + i, col (l&15)  [verified round 2]

template <int NOUT, bool A_FP32, int OMODE>
__device__ __forceinline__ void gemm_body(
    int bid, const void* __restrict__ Aptr, const uint16_t* __restrict__ Wt,
    const float* __restrict__ bias, float* __restrict__ outF,
    uint16_t* __restrict__ outB, uint8_t* __restrict__ outQ,
    const float* __restrict__ rowscale, int M)
{
    constexpr int NT = NOUT / 16;
    const int tid = threadIdx.x;
    const int w = tid >> 6;
    const int l = tid & 63;
    const int lg = l >> 4;   // k-group
    const int lr = l & 15;   // row-in-tile (A) / col-in-tile (B,D)
    const int rbase = bid * 128 + w * 32;
    const int r0c = min(rbase + lr, M - 1);
    const int r1c = min(rbase + 16 + lr, M - 1);

    f32x4 acc[2][NT] = {};

    for (int k0 = 0; k0 < K; k0 += 32) {
        const int ka = k0 + lg * 8;
        bf16x8 a0, a1;
        if constexpr (A_FP32) {
            const float* A = (const float*)Aptr;
            const float* p0 = A + (size_t)r0c * K + ka;
            const float* p1 = A + (size_t)r1c * K + ka;
            float4 u0 = *(const float4*)p0, v0 = *(const float4*)(p0 + 4);
            float4 u1 = *(const float4*)p1, v1 = *(const float4*)(p1 + 4);
            a0[0] = (__bf16)u0.x; a0[1] = (__bf16)u0.y; a0[2] = (__bf16)u0.z; a0[3] = (__bf16)u0.w;
            a0[4] = (__bf16)v0.x; a0[5] = (__bf16)v0.y; a0[6] = (__bf16)v0.z; a0[7] = (__bf16)v0.w;
            a1[0] = (__bf16)u1.x; a1[1] = (__bf16)u1.y; a1[2] = (__bf16)u1.z; a1[3] = (__bf16)u1.w;
            a1[4] = (__bf16)v1.x; a1[5] = (__bf16)v1.y; a1[6] = (__bf16)v1.z; a1[7] = (__bf16)v1.w;
        } else {
            const uint16_t* A = (const uint16_t*)Aptr;
            a0 = *reinterpret_cast<const bf16x8*>(A + (size_t)r0c * K + ka);
            a1 = *reinterpret_cast<const bf16x8*>(A + (size_t)r1c * K + ka);
        }
#pragma unroll
        for (int ct = 0; ct < NT; ++ct) {
            bf16x8 b = *reinterpret_cast<const bf16x8*>(Wt + (size_t)(ct * 16 + lr) * K + ka);
            acc[0][ct] = __builtin_amdgcn_mfma_f32_16x16x32_bf16(a0, b, acc[0][ct], 0, 0, 0);
            acc[1][ct] = __builtin_amdgcn_mfma_f32_16x16x32_bf16(a1, b, acc[1][ct], 0, 0, 0);
        }
    }

    float bv[NT];
    if constexpr (OMODE == 0 || OMODE == 1) {
#pragma unroll
        for (int ct = 0; ct < NT; ++ct) bv[ct] = bias[ct * 16 + lr];
    }

    if constexpr (OMODE == 1) {
#pragma unroll
        for (int t = 0; t < 2; ++t) {
#pragma unroll
            for (int i = 0; i < 4; ++i) {
                float v[NT];
                float m = -3.0e38f;
#pragma unroll
                for (int ct = 0; ct < NT; ++ct) {
                    v[ct] = acc[t][ct][i] + bv[ct];
                    m = fmaxf(m, v[ct]);
                }
#pragma unroll
                for (int o = 8; o >= 1; o >>= 1) m = fmaxf(m, __shfl_xor(m, o));
                float s = 0.f;
#pragma unroll
                for (int ct = 0; ct < NT; ++ct) s += __expf(v[ct] - m);
#pragma unroll
                for (int o = 8; o >= 1; o >>= 1) s += __shfl_xor(s, o);
                float lse = m + __logf(s);
                int rr = rbase + t * 16 + lg * 4 + i;
                if (rr < M) {
#pragma unroll
                    for (int ct = 0; ct < NT; ++ct)
                        outF[(size_t)rr * NOUT + ct * 16 + lr] = v[ct] - lse;
                }
            }
        }
    } else {
#pragma unroll
        for (int t = 0; t < 2; ++t) {
#pragma unroll
            for (int i = 0; i < 4; ++i) {
                int rr = rbase + t * 16 + lg * 4 + i;
                if (rr < M) {
                    float sc = 1.0f;
                    if constexpr (OMODE == 2) sc = rowscale[rr];
#pragma unroll
                    for (int ct = 0; ct < NT; ++ct) {
                        float v = acc[t][ct][i];
                        size_t o = (size_t)rr * NOUT + ct * 16 + lr;
                        if constexpr (OMODE == 0) {
                            outB[o] = f2bf(v + bv[ct]);
                        } else {  // OMODE == 2: fp8 e4m3 message
                            v *= sc;
                            int pk = __builtin_amdgcn_cvt_pk_fp8_f32(v, v, 0, false);
                            outQ[o] = (uint8_t)(pk & 0xff);
                        }
                    }
                }
            }
        }
    }
}

template <int NOUT, bool A_FP32, int OMODE>
__global__ __launch_bounds__(256) void mfma_gemm(
    const void* __restrict__ Aptr, const uint16_t* __restrict__ Wt,
    const float* __restrict__ bias, float* __restrict__ outF,
    uint16_t* __restrict__ outB, uint8_t* __restrict__ outQ,
    const float* __restrict__ rowscale, int M)
{
    gemm_body<NOUT, A_FP32, OMODE>(blockIdx.x, Aptr, Wt, bias, outF, outB, outQ, rowscale, M);
}

// k3: input GEMM (blocks 0..gblocks-1) + s3 scatter (blocks gblocks..)
__global__ __launch_bounds__(256) void fused_gin_s3(
    const void* __restrict__ Aptr, const uint16_t* __restrict__ Wt,
    const float* __restrict__ bias, uint16_t* __restrict__ outB, int M, int gblocks,
    const int* __restrict__ src, const int* __restrict__ dst,
    int* __restrict__ gcur, int* __restrict__ ebuf, int E)
{
    int b = blockIdx.x;
    if (b < gblocks)
        gemm_body<128, true, 0>(b, Aptr, Wt, bias, nullptr, outB, nullptr, nullptr, M);
    else
        s3_body(b - gblocks, src, dst, gcur, ebuf, E);
}

// ---------------- aggregation + bias + tanh + rezero (bf16 residual) ----------------
// (unchanged from round 10 — at its L3-random-rate floor)

__global__ __launch_bounds__(256) void agg_kernel(
    const uint8_t* __restrict__ B, uint16_t* __restrict__ A,
    const float* __restrict__ dinv, const int* __restrict__ off,
    const int* __restrict__ csr, const float* __restrict__ bconv,
    const float* __restrict__ alpha, const float* __restrict__ beta,
    int n, int E)
{
    int gid = blockIdx.x * 256 + threadIdx.x;
    int d = gid >> 6;
    int lane = threadIdx.x & 63;
    if (d >= n) return;

    const int half = lane >> 5;
    const int c0 = (lane & 31) * 4;  // 4 features (bytes) per lane
    f32x2 acc01 = {0.f, 0.f}, acc23 = {0.f, 0.f};
    const int s0 = off[d], s1 = off[d + 1];

    for (int j0 = s0; j0 < s1; j0 += 64) {
        int idx = j0 + lane;
        int sv = csr[min(idx, E - 1)];  // byte offset of src row
        const int cnt = min(64, s1 - j0);
        const int cf = cnt & ~7;
        int it = 0;
        for (; it < cf; it += 8) {      // full batch: 8 edges, 4 loads, no masks
            uint32_t u[4];
#pragma unroll
            for (int q = 0; q < 4; ++q) {
                int o = __shfl(sv, it + 2 * q + half);
                u[q] = *(const uint32_t*)(B + o + c0);
            }
#pragma unroll
            for (int q = 0; q < 4; ++q) {
                acc01 += __builtin_amdgcn_cvt_pk_f32_fp8((int)u[q], false);
                acc23 += __builtin_amdgcn_cvt_pk_f32_fp8((int)u[q], true);
            }
        }
        if (it < cnt) {                 // tail batch: predicated
            uint32_t u[4];
#pragma unroll
            for (int q = 0; q < 4; ++q) {
                int e = it + 2 * q + half;
                int o = __shfl(sv, e);
                u[q] = (e < cnt) ? *(const uint32_t*)(B + o + c0) : 0u;
            }
#pragma unroll
            for (int q = 0; q < 4; ++q) {
                acc01 += __builtin_amdgcn_cvt_pk_f32_fp8((int)u[q], false);
                acc23 += __builtin_amdgcn_cvt_pk_f32_fp8((int)u[q], true);
            }
        }
    }
    float a0 = acc01[0], a1 = acc01[1], a2 = acc23[0], a3 = acc23[1];
    // combine the two half-wave partial sums (lane&31 preserved under xor 32)
    a0 += __shfl_xor(a0, 32); a1 += __shfl_xor(a1, 32);
    a2 += __shfl_xor(a2, 32); a3 += __shfl_xor(a3, 32);
    // self loop, added once AFTER the combine
    {
        uint32_t u = *(const uint32_t*)(B + ((size_t)d << 7) + c0);
        f32x2 lo = __builtin_amdgcn_cvt_pk_f32_fp8((int)u, false);
        f32x2 hi = __builtin_amdgcn_cvt_pk_f32_fp8((int)u, true);
        a0 += lo[0]; a1 += lo[1]; a2 += hi[0]; a3 += hi[1];
    }

    float dd = dinv[d];
    float al = alpha[0], be = beta[0];
    float4 bb = *(const float4*)(bconv + c0);
    uint2 ip = *(const uint2*)(A + (size_t)d * K + c0);
    float o0 = be * blo(ip.x) + al * fast_tanh(fmaf(dd, a0, bb.x));
    float o1 = be * bhi(ip.x) + al * fast_tanh(fmaf(dd, a1, bb.y));
    float o2 = be * blo(ip.y) + al * fast_tanh(fmaf(dd, a2, bb.z));
    float o3 = be * bhi(ip.y) + al * fast_tanh(fmaf(dd, a3, bb.w));
    if (half == 0) {
        uint2 pk;
        asm("v_cvt_pk_bf16_f32 %0, %1, %2" : "=v"(pk.x) : "v"(o0), "v"(o1));
        asm("v_cvt_pk_bf16_f32 %0, %1, %2" : "=v"(pk.y) : "v"(o2), "v"(o3));
        *(uint2*)(A + (size_t)d * K + c0) = pk;
    }
}

// ---------------------------------------------------------------------------

extern "C" void kernel_launch(void* const* d_in, const int* in_sizes, int n_in,
                              void* d_out, int out_size, void* d_ws, size_t ws_size,
                              hipStream_t stream)
{
    const float* x      = (const float*)d_in[0];
    const int*   ei     = (const int*)d_in[1];
    const float* W_in   = (const float*)d_in[2];
    const float* b_in   = (const float*)d_in[3];
    const float* W_conv = (const float*)d_in[4];
    const float* b_conv = (const float*)d_in[5];
    const float* alpha  = (const float*)d_in[6];
    const float* beta   = (const float*)d_in[7];
    const float* W_out  = (const float*)d_in[8];
    const float* b_out  = (const float*)d_in[9];
    float* out = (float*)d_out;

    const int N = in_sizes[0] / K;   // 100000
    const int E = in_sizes[1] / 2;   // 1600000
    const int L = in_sizes[6];       // 4

    const int* src = ei;
    const int* dst = ei + E;

    // workspace carve (16B-aligned by construction)
    char* p = (char*)d_ws;
    uint16_t* Abf = (uint16_t*)p;      p += (size_t)N * K * sizeof(uint16_t);  // 25.6 MB
    uint8_t* Bq8 = (uint8_t*)p;        p += (size_t)N * K * sizeof(uint8_t);   // 12.8 MB
    uint16_t* Wt_in = (uint16_t*)p;    p += (size_t)K * K * sizeof(uint16_t);
    uint16_t* Wt_conv = (uint16_t*)p;  p += (size_t)4 * K * K * sizeof(uint16_t);
    uint16_t* Wt_out = (uint16_t*)p;   p += (size_t)64 * K * sizeof(uint16_t);
    float* dinv = (float*)p;           p += (size_t)N * sizeof(float);
    int* off = (int*)p;                p += (size_t)(N + 1) * sizeof(int);
    int* csr = (int*)p;                p += (size_t)E * sizeof(int);
    int* ghist = (int*)p;              p += 1024 * sizeof(int);
    int* gbase = (int*)p;              p += 1025 * sizeof(int);
    int* gcur = (int*)p;               p += 1024 * sizeof(int);
    int* ebuf = (int*)p;               p += (size_t)E * sizeof(int);  // CSR-build staging

    const int gblocks = (N + 127) / 128;           // 782
    const int s3blocks = (E + 8191) / 8192;        // 196

    // ---- CSR build + weight prep (fused/overlapped) ----
    hipMemsetAsync(ghist, 0, 1024 * sizeof(int), stream);
    fused_s1_wconv<<<256 + 352, 256, 0, stream>>>(
        dst, ghist, E, W_in, W_conv, W_out, Wt_in, Wt_conv, Wt_out);
    s2_scan<<<1, 1024, 0, stream>>>(ghist, gbase, gcur, off, N, E);
    // input GEMM (h0 = x@W_in + b_in -> Abf) overlapped with edge scatter
    fused_gin_s3<<<gblocks + s3blocks, 256, 0, stream>>>(
        x, Wt_in, b_in, Abf, N, gblocks, src, dst, gcur, ebuf, E);
    s4_finalize<<<gblocks, 256, 0, stream>>>(gbase, ebuf, csr, off, dinv, N, E);

    for (int l = 0; l < L; ++l) {
        // Bq8 = fp8( dinv[row] * (Abf @ Wc) )   (pre-scaled messages)
        mfma_gemm<128, false, 2><<<gblocks, 256, 0, stream>>>(
            Abf, Wt_conv + (size_t)l * K * K, nullptr, nullptr, nullptr, Bq8, dinv, N);
        agg_kernel<<<(N * 64 + 255) / 256, 256, 0, stream>>>(
            Bq8, Abf, dinv, off, csr, b_conv + (size_t)l * K,
            alpha + l, beta + l, N, E);
    }
    // logits = Abf @ W_out + b_out, fused log_softmax, fp32 to d_out
    mfma_gemm<64, false, 1><<<gblocks, 256, 0, stream>>>(
        Abf, Wt_out, b_out, out, nullptr, nullptr, nullptr, N);
}